// Round 2
// baseline (118.169 us; speedup 1.0000x reference)
//
#include <hip/hip_runtime.h>
#include <hip/hip_bf16.h>
#include <math.h>

#define NN 8192
#define DD 256
#define CHUNK 2048
constexpr float ALPHA = 0.2f;

typedef __attribute__((ext_vector_type(4))) float f32x4;
typedef __attribute__((ext_vector_type(8))) short bf16x8;

// ---------------- conv: X -> Xhi/Xlo (bf16 split) ----------------
__global__ __launch_bounds__(256) void k_convX(const float* __restrict__ X,
                                               short* __restrict__ Xhi,
                                               short* __restrict__ Xlo) {
    int i = blockIdx.x * 256 + threadIdx.x;   // float4 index
    float4 v = ((const float4*)X)[i];
    float f[4] = {v.x, v.y, v.z, v.w};
    short h[4], l[4];
    #pragma unroll
    for (int q = 0; q < 4; ++q) {
        __hip_bfloat16 hb = __float2bfloat16(f[q]);
        float hf = __bfloat162float(hb);
        __hip_bfloat16 lb = __float2bfloat16(f[q] - hf);
        h[q] = __builtin_bit_cast(short, hb);
        l[q] = __builtin_bit_cast(short, lb);
    }
    *(short4*)(Xhi + (size_t)i * 4) = make_short4(h[0], h[1], h[2], h[3]);
    *(short4*)(Xlo + (size_t)i * 4) = make_short4(l[0], l[1], l[2], l[3]);
}

// ---------------- conv+transpose: W[k][n] -> WhiT/WloT [n][k] ----------------
__global__ __launch_bounds__(256) void k_convW(const float* __restrict__ W,
                                               short* __restrict__ WhiT,
                                               short* __restrict__ WloT) {
    __shared__ float tile[64][65];
    const int n0 = (blockIdx.x & 3) * 64;
    const int k0 = (blockIdx.x >> 2) * 64;
    const int c = threadIdx.x & 63;
    const int rg = threadIdx.x >> 6;          // wave id 0..3
    #pragma unroll
    for (int i = 0; i < 16; ++i) {
        int r = rg * 16 + i;
        tile[r][c] = W[(size_t)(k0 + r) * DD + n0 + c];
    }
    __syncthreads();
    #pragma unroll
    for (int i = 0; i < 16; ++i) {
        int rw = rg * 16 + i;                 // local n
        float x = tile[c][rw];
        __hip_bfloat16 hb = __float2bfloat16(x);
        float hf = __bfloat162float(hb);
        __hip_bfloat16 lb = __float2bfloat16(x - hf);
        WhiT[(size_t)(n0 + rw) * DD + k0 + c] = __builtin_bit_cast(short, hb);
        WloT[(size_t)(n0 + rw) * DD + k0 + c] = __builtin_bit_cast(short, lb);
    }
}

// ---------------- Kernel 1: Wh = X @ W via split-bf16 MFMA ----------------
// BM=128, BN=64, BK=32; 4 waves (2x2); wave tile 64x32 = 4x2 frags of 16x16.
#define LDA 40  // padded LDS row stride (elements); row byte stride 80 = 16*5
__global__ __launch_bounds__(256) void k_gemm(const short* __restrict__ Xhi,
                                              const short* __restrict__ Xlo,
                                              const short* __restrict__ WhiT,
                                              const short* __restrict__ WloT,
                                              float* __restrict__ Wh) {
    __shared__ short sAh[128 * LDA], sAl[128 * LDA];
    __shared__ short sBh[64 * LDA],  sBl[64 * LDA];
    const int tid = threadIdx.x;
    const int lane = tid & 63;
    const int wid = tid >> 6;
    const int wm = wid >> 1, wn = wid & 1;
    const int row0 = (blockIdx.x >> 2) * 128;
    const int col0 = (blockIdx.x & 3) * 64;
    f32x4 acc[4][2] = {};
    for (int k0 = 0; k0 < DD; k0 += 32) {
        // stage A (128 rows x 32k, hi+lo): 512 16B segs per buffer, 2/thread
        #pragma unroll
        for (int i = 0; i < 2; ++i) {
            int idx = tid + i * 256;
            int r = idx >> 2, sg = idx & 3;
            *(int4*)(sAh + r * LDA + sg * 8) =
                *(const int4*)(Xhi + (size_t)(row0 + r) * DD + k0 + sg * 8);
            *(int4*)(sAl + r * LDA + sg * 8) =
                *(const int4*)(Xlo + (size_t)(row0 + r) * DD + k0 + sg * 8);
        }
        // stage B (64 n-rows x 32k from W^T): 256 segs per buffer, 1/thread
        {
            int r = tid >> 2, sg = tid & 3;
            *(int4*)(sBh + r * LDA + sg * 8) =
                *(const int4*)(WhiT + (size_t)(col0 + r) * DD + k0 + sg * 8);
            *(int4*)(sBl + r * LDA + sg * 8) =
                *(const int4*)(WloT + (size_t)(col0 + r) * DD + k0 + sg * 8);
        }
        __syncthreads();
        const int kb = (lane >> 4) * 8;
        const int ar = wm * 64 + (lane & 15);
        const int br = wn * 32 + (lane & 15);
        bf16x8 ah[4], al[4], bh[2], bl[2];
        #pragma unroll
        for (int mi = 0; mi < 4; ++mi) {
            ah[mi] = *(const bf16x8*)(sAh + (ar + mi * 16) * LDA + kb);
            al[mi] = *(const bf16x8*)(sAl + (ar + mi * 16) * LDA + kb);
        }
        #pragma unroll
        for (int ni = 0; ni < 2; ++ni) {
            bh[ni] = *(const bf16x8*)(sBh + (br + ni * 16) * LDA + kb);
            bl[ni] = *(const bf16x8*)(sBl + (br + ni * 16) * LDA + kb);
        }
        #pragma unroll
        for (int mi = 0; mi < 4; ++mi)
            #pragma unroll
            for (int ni = 0; ni < 2; ++ni) {
                acc[mi][ni] = __builtin_amdgcn_mfma_f32_16x16x32_bf16(ah[mi], bh[ni], acc[mi][ni], 0, 0, 0);
                acc[mi][ni] = __builtin_amdgcn_mfma_f32_16x16x32_bf16(ah[mi], bl[ni], acc[mi][ni], 0, 0, 0);
                acc[mi][ni] = __builtin_amdgcn_mfma_f32_16x16x32_bf16(al[mi], bh[ni], acc[mi][ni], 0, 0, 0);
            }
        __syncthreads();
    }
    const int orow = row0 + wm * 64 + (lane >> 4) * 4;
    const int ocol = col0 + wn * 32 + (lane & 15);
    #pragma unroll
    for (int mi = 0; mi < 4; ++mi)
        #pragma unroll
        for (int ni = 0; ni < 2; ++ni)
            #pragma unroll
            for (int r = 0; r < 4; ++r)
                Wh[(size_t)(orow + mi * 16 + r) * DD + ocol + ni * 16] = acc[mi][ni][r];
}

// ---------------- Kernel 1b: f1 = Wh@a1, f2 = Wh@a2 ----------------
__global__ __launch_bounds__(256) void k_f12(const float* __restrict__ Wh,
                                             const float* __restrict__ a1,
                                             const float* __restrict__ a2,
                                             float* __restrict__ f1,
                                             float* __restrict__ f2) {
    const int wid = threadIdx.x >> 6;
    const int lane = threadIdx.x & 63;
    const int row = blockIdx.x * 4 + wid;
    float4 w  = *(const float4*)(Wh + (size_t)row * DD + lane * 4);
    float4 v1 = *(const float4*)(a1 + lane * 4);
    float4 v2 = *(const float4*)(a2 + lane * 4);
    float s1 = w.x * v1.x + w.y * v1.y + w.z * v1.z + w.w * v1.w;
    float s2 = w.x * v2.x + w.y * v2.y + w.z * v2.z + w.w * v2.w;
    #pragma unroll
    for (int o = 32; o; o >>= 1) {
        s1 += __shfl_down(s1, o);
        s2 += __shfl_down(s2, o);
    }
    if (lane == 0) { f1[row] = s1; f2[row] = s2; }
}

// ---------------- Kernel 2: sparse GAT softmax-aggregate ----------------
// One block per row. Compact edges per 2048-col chunk into LDS; online softmax
// across chunks. Edge loop split across 4 waves (k = wid mod 4); each lane
// gathers a float4 of the Wh row (coalesced 1KB/wave). Cross-wave combine in LDS.
__global__ __launch_bounds__(256) void k_gat(const float* __restrict__ adj,
                                             const float* __restrict__ Wh,
                                             const float* __restrict__ f1,
                                             const float* __restrict__ f2,
                                             float* __restrict__ out) {
    __shared__ int   s_j[CHUNK];
    __shared__ float s_e[CHUNK];
    __shared__ int   s_cnt;
    __shared__ float s_red[4];
    __shared__ float s_acc[4][DD];
    __shared__ float s_sum[4];
    const int row = blockIdx.x;
    const int tid = threadIdx.x;
    const int lane = tid & 63, wid = tid >> 6;
    const float f1i = f1[row];
    float m = -INFINITY, ssum = 0.f;
    float ax = 0.f, ay = 0.f, az = 0.f, aw = 0.f;
    const float4* arow = (const float4*)(adj + (size_t)row * NN);
    for (int c0 = 0; c0 < NN; c0 += CHUNK) {
        if (tid == 0) s_cnt = 0;
        __syncthreads();
        float lmax = -INFINITY;
        #pragma unroll
        for (int i = 0; i < CHUNK / 1024; ++i) {
            int fidx = (c0 >> 2) + tid + i * 256;
            float4 a = arow[fidx];
            int jb = c0 + (tid + i * 256) * 4;
            float av[4] = {a.x, a.y, a.z, a.w};
            #pragma unroll
            for (int q = 0; q < 4; ++q) {
                if (av[q] > 0.f) {
                    int j = jb + q;
                    float e = f1i + f2[j];
                    e = e > 0.f ? e : ALPHA * e;         // leaky_relu
                    int slot = atomicAdd(&s_cnt, 1);
                    s_j[slot] = j;
                    s_e[slot] = e;
                    lmax = fmaxf(lmax, e);
                }
            }
        }
        #pragma unroll
        for (int o = 32; o; o >>= 1) lmax = fmaxf(lmax, __shfl_down(lmax, o));
        if (lane == 0) s_red[wid] = lmax;
        __syncthreads();                 // pushes + cnt + s_red visible
        const int cnt = s_cnt;
        if (cnt > 0) {
            float Mc = fmaxf(fmaxf(s_red[0], s_red[1]), fmaxf(s_red[2], s_red[3]));
            float mnew = fmaxf(m, Mc);
            float scale = __expf(m - mnew);   // m=-inf -> 0, zeroes empty acc/ssum
            ax *= scale; ay *= scale; az *= scale; aw *= scale;
            ssum *= scale; m = mnew;
            for (int k = wid; k < cnt; k += 4) {
                int j = s_j[k];
                float w = __expf(s_e[k] - m);
                ssum += w;
                float4 v = *(const float4*)(Wh + (size_t)j * DD + lane * 4);
                ax = fmaf(w, v.x, ax);
                ay = fmaf(w, v.y, ay);
                az = fmaf(w, v.z, az);
                aw = fmaf(w, v.w, aw);
            }
        }
        __syncthreads();                 // done reading before next reset
    }
    *(float4*)&s_acc[wid][lane * 4] = make_float4(ax, ay, az, aw);
    if (lane == 0) s_sum[wid] = ssum;
    __syncthreads();
    float denom = s_sum[0] + s_sum[1] + s_sum[2] + s_sum[3];
    float tot = s_acc[0][tid] + s_acc[1][tid] + s_acc[2][tid] + s_acc[3][tid];
    float o = tot / denom;               // self loop -> denom > 0
    out[(size_t)row * DD + tid] = o > 0.f ? o : 0.f;
}

extern "C" void kernel_launch(void* const* d_in, const int* in_sizes, int n_in,
                              void* d_out, int out_size, void* d_ws, size_t ws_size,
                              hipStream_t stream) {
    const float* X   = (const float*)d_in[0];
    const float* adj = (const float*)d_in[1];
    // d_in[2] = cmt_weight (unused by SPGAT)
    const float* W   = (const float*)d_in[3];
    const float* a1  = (const float*)d_in[4];
    const float* a2  = (const float*)d_in[5];
    float* out = (float*)d_out;

    short* Xhi  = (short*)d_ws;                     // N*D bf16
    short* Xlo  = Xhi + (size_t)NN * DD;
    short* WhiT = Xlo + (size_t)NN * DD;            // D*D bf16 (transposed)
    short* WloT = WhiT + (size_t)DD * DD;
    float* Wh   = (float*)(WloT + (size_t)DD * DD); // N*D fp32 (16B-aligned)
    float* f1   = Wh + (size_t)NN * DD;
    float* f2   = f1 + NN;

    k_convX<<<(NN * DD / 4) / 256, 256, 0, stream>>>(X, Xhi, Xlo);
    k_convW<<<16, 256, 0, stream>>>(W, WhiT, WloT);
    k_gemm<<<(NN / 128) * (DD / 64), 256, 0, stream>>>(Xhi, Xlo, WhiT, WloT, Wh);
    k_f12<<<NN / 4, 256, 0, stream>>>(Wh, a1, a2, f1, f2);
    k_gat<<<NN, 256, 0, stream>>>(adj, Wh, f1, f2, out);
}